// Round 5
// baseline (409.093 us; speedup 1.0000x reference)
//
#include <hip/hip_runtime.h>
#include <stdint.h>

typedef unsigned short u16;
typedef float    f32x4  __attribute__((ext_vector_type(4)));
typedef __bf16   bf16x8 __attribute__((ext_vector_type(8)));
typedef u16      u16x8  __attribute__((ext_vector_type(8)));
typedef u16      u16x4  __attribute__((ext_vector_type(4)));
typedef float    f32x4v __attribute__((ext_vector_type(4)));

#define B_SZ   2
#define S_LEN  2048
#define HDIM   2048
#define NH_    16
#define NKV_   2
#define HD_    128
#define M_ROWS 4096   // B*S
#define NQKV   2560   // (NH + 2*NKV) * HD

static __device__ __forceinline__ u16 f2bf(float f) {
    uint32_t u = __builtin_bit_cast(uint32_t, f);
    uint32_t r = (u + 0x7fffu + ((u >> 16) & 1u)) >> 16;
    return (u16)r;
}
static __device__ __forceinline__ float bf2f(u16 b) {
    uint32_t u = ((uint32_t)b) << 16;
    return __builtin_bit_cast(float, u);
}
static __device__ __forceinline__ void gload_lds16(const void* g, void* l) {
    __builtin_amdgcn_global_load_lds((__attribute__((address_space(1))) void*)(g),
                                     (__attribute__((address_space(3))) void*)(l),
                                     16, 0, 0);
}

// ---------------- elementwise converts ----------------
__global__ void cvt_f32_bf16(const float* __restrict__ in, u16* __restrict__ out, int n4) {
    int i = blockIdx.x * blockDim.x + threadIdx.x;
    if (i >= n4) return;
    f32x4v v = ((const f32x4v*)in)[i];
    u16x4 o;
    o[0] = f2bf(v[0]); o[1] = f2bf(v[1]); o[2] = f2bf(v[2]); o[3] = f2bf(v[3]);
    ((u16x4*)out)[i] = o;
}

__global__ void concat_bias(const float* __restrict__ qb, const float* __restrict__ kb,
                            const float* __restrict__ vb, float* __restrict__ out) {
    int i = blockIdx.x * blockDim.x + threadIdx.x;
    if (i >= NQKV) return;
    if (i < 2048)       out[i] = qb[i];
    else if (i < 2304)  out[i] = kb[i - 2048];
    else                out[i] = vb[i - 2304];
}

__global__ void rope_table(float* __restrict__ tc, float* __restrict__ ts) {
    int p = blockIdx.x;
    int d = threadIdx.x;   // 64 threads
    float inv = expf(-(float)d * 0.14391156831212787f);
    float ang = (float)p * inv;
    float s, c;
    sincosf(ang, &s, &c);
    tc[p * 64 + d] = c;
    ts[p * 64 + d] = s;
}

// ---------------- GEMM: C[m,n] = sum_k A[m,k]*W[n,k] (+bias[n]) ----------------
template <typename OutT, bool HAS_BIAS>
__global__ __launch_bounds__(256) void gemm_bt(const u16* __restrict__ A,
                                               const u16* __restrict__ W,
                                               const float* __restrict__ bias,
                                               OutT* __restrict__ C,
                                               int M, int N, int K) {
    __shared__ u16 sA[128 * 32];
    __shared__ u16 sB[128 * 32];
    const int tid = threadIdx.x;
    const int lane = tid & 63;
    const int w = tid >> 6;
    const int wr = w >> 1, wc = w & 1;
    const int l15 = lane & 15, l4 = lane >> 4;
    const int brow = blockIdx.y * 128;
    const int bcol = blockIdx.x * 128;

    f32x4 acc[4][4];
#pragma unroll
    for (int m = 0; m < 4; ++m)
#pragma unroll
        for (int n = 0; n < 4; ++n) acc[m][n] = (f32x4){0.f, 0.f, 0.f, 0.f};

    const int nk = K >> 5;
    for (int kt = 0; kt < nk; ++kt) {
        __syncthreads();
#pragma unroll
        for (int i = 0; i < 2; ++i) {
            int e = i * 2048 + tid * 8;
            int row = e >> 5, col = e & 31;
            gload_lds16(A + (size_t)(brow + row) * K + kt * 32 + col, &sA[e]);
            gload_lds16(W + (size_t)(bcol + row) * K + kt * 32 + col, &sB[e]);
        }
        __syncthreads();
        bf16x8 af[4], bfr[4];
#pragma unroll
        for (int m = 0; m < 4; ++m)
            af[m] = *(const bf16x8*)&sA[(wr * 64 + m * 16 + l15) * 32 + l4 * 8];
#pragma unroll
        for (int n = 0; n < 4; ++n)
            bfr[n] = *(const bf16x8*)&sB[(wc * 64 + n * 16 + l15) * 32 + l4 * 8];
#pragma unroll
        for (int m = 0; m < 4; ++m)
#pragma unroll
            for (int n = 0; n < 4; ++n)
                acc[m][n] = __builtin_amdgcn_mfma_f32_16x16x32_bf16(af[m], bfr[n], acc[m][n], 0, 0, 0);
    }

#pragma unroll
    for (int m = 0; m < 4; ++m) {
#pragma unroll
        for (int n = 0; n < 4; ++n) {
            int cn = bcol + wc * 64 + n * 16 + l15;
            float bv = 0.f;
            if constexpr (HAS_BIAS) bv = bias[cn];
#pragma unroll
            for (int i = 0; i < 4; ++i) {
                int r = brow + wr * 64 + m * 16 + l4 * 4 + i;
                float v = acc[m][n][i] + bv;
                if constexpr (sizeof(OutT) == 2) {
                    C[(size_t)r * N + cn] = (OutT)f2bf(v);
                } else {
                    C[(size_t)r * N + cn] = v;
                }
            }
        }
    }
}

// ---------------- RoPE + layout ----------------
__global__ void rope_apply(const u16* __restrict__ qkv, const int* __restrict__ pos,
                           const float* __restrict__ tc, const float* __restrict__ ts,
                           u16* __restrict__ Qr, u16* __restrict__ Kr, u16* __restrict__ Vr) {
    int idx = blockIdx.x * blockDim.x + threadIdx.x;
    if (idx >= M_ROWS * 20 * 64) return;
    int d = idx & 63;
    int sec = (idx >> 6) % 20;
    int row = idx / (20 * 64);
    int b = row >> 11, s = row & 2047;
    int p = pos[row];
    const u16* q = qkv + (size_t)row * NQKV;
    if (sec < 16) {
        float c = tc[p * 64 + d], sn = ts[p * 64 + d];
        float x1 = bf2f(q[sec * 128 + d]);
        float x2 = bf2f(q[sec * 128 + d + 64]);
        size_t o = (((size_t)(b * NH_ + sec)) * S_LEN + s) * HD_ + d;
        Qr[o] = f2bf(x1 * c - x2 * sn);
        Qr[o + 64] = f2bf(x2 * c + x1 * sn);
    } else if (sec < 18) {
        int hk = sec - 16;
        float c = tc[p * 64 + d], sn = ts[p * 64 + d];
        float x1 = bf2f(q[2048 + hk * 128 + d]);
        float x2 = bf2f(q[2048 + hk * 128 + d + 64]);
        size_t o = (((size_t)(b * NKV_ + hk)) * S_LEN + s) * HD_ + d;
        Kr[o] = f2bf(x1 * c - x2 * sn);
        Kr[o + 64] = f2bf(x2 * c + x1 * sn);
    } else {
        int hv = sec - 18;
        size_t o = (((size_t)(b * NKV_ + hv)) * S_LEN + s) * HD_ + d;
        Vr[o] = q[2304 + hv * 128 + d];
        Vr[o + 64] = q[2304 + hv * 128 + d + 64];
    }
}

// ---------------- flash attention (causal, GQA) ----------------
// grid: (16, B*NH). Each block processes q-tiles {x, 31-x} (uniform 33 KV-tiles).
// 4 waves/block, 16 q-rows/wave, KV tile = 64. Double-buffered, defer-max softmax.
#define QB 64
#define KVB 64
#define VT_STRIDE 72   // 144B rows: 16B-aligned b128, even bank-quad spread
#define SP_STRIDE 40   // 80B rows: 16B-aligned b128, even bank-quad spread
__global__ __launch_bounds__(256) void attn_kernel(const u16* __restrict__ Qr,
                                                   const u16* __restrict__ Kr,
                                                   const u16* __restrict__ Vr,
                                                   u16* __restrict__ Ao) {
    __shared__ u16 sK[2][KVB * HD_];         // XOR-swizzled rows [key][d]  (2x16KB)
    __shared__ u16 sVt[2][HD_ * VT_STRIDE];  // transposed [d][key]         (2x18KB)
    __shared__ u16 sP[4][16 * SP_STRIDE];    // per-wave P tile (32-key pass)

    const int tid = threadIdx.x;
    const int lane = tid & 63;
    const int w = tid >> 6;
    const int l15 = lane & 15;
    const int l4 = lane >> 4;

    const int bh = blockIdx.y;
    const int b = bh >> 4;
    const int h = bh & 15;
    const int kvh = h >> 3;
    const size_t kvbase = ((size_t)(b * NKV_ + kvh)) * S_LEN * HD_;

    // K staging mapping (pre-swizzled global source, linear LDS dest)
    int kg_off[4], kl_off[4];
#pragma unroll
    for (int i = 0; i < 4; ++i) {
        int e = i * 2048 + tid * 8;
        int L = e * 2;
        int key = L >> 8;
        int inner = (L & 255) ^ ((key & 7) << 4);
        kg_off[i] = key * HD_ + (inner >> 1);
        kl_off[i] = e;
    }
    // V staging mapping: thread -> (key, 32-d chunk)
    const int vkey = tid & 63;
    const int vd0 = (tid >> 6) * 32;

    const float scale = 0.08838834764831845f;  // 1/sqrt(128)

    for (int pass = 0; pass < 2; ++pass) {
        const int qbk = pass ? (31 - blockIdx.x) : blockIdx.x;
        const int qr0 = qbk * QB + w * 16;
        const size_t qbase = (((size_t)(b * NH_ + h)) * S_LEN + qr0 + l15) * HD_;
        bf16x8 qf[4];
#pragma unroll
        for (int c = 0; c < 4; ++c)
            qf[c] = *(const bf16x8*)(Qr + qbase + c * 32 + l4 * 8);

        f32x4 oa[8];
#pragma unroll
        for (int c = 0; c < 8; ++c) oa[c] = (f32x4){0.f, 0.f, 0.f, 0.f};
        float mrow[4], lsum[4];
#pragma unroll
        for (int i = 0; i < 4; ++i) { mrow[i] = -1e30f; lsum[i] = 0.f; }

        const int nt = qbk + 1;

        // ---- prologue: stage tile 0 into buffer 0 ----
        {
            const u16* kp = Kr + kvbase;
#pragma unroll
            for (int i = 0; i < 4; ++i) gload_lds16(kp + kg_off[i], &sK[0][kl_off[i]]);
            const u16* src = Vr + kvbase + (size_t)vkey * HD_ + vd0;
            u16x8 v0[4];
#pragma unroll
            for (int c = 0; c < 4; ++c) v0[c] = *(const u16x8*)(src + c * 8);
#pragma unroll
            for (int c = 0; c < 4; ++c)
#pragma unroll
                for (int j = 0; j < 8; ++j)
                    sVt[0][(vd0 + c * 8 + j) * VT_STRIDE + vkey] = v0[c][j];
        }
        __syncthreads();

        for (int t = 0; t < nt; ++t) {
            const int cur = t & 1;
            const int k0 = t * KVB;
            u16x8 vn[4];
            const bool pre = (t + 1 < nt);
            if (pre) {
                const u16* kp = Kr + kvbase + (size_t)(k0 + KVB) * HD_;
#pragma unroll
                for (int i = 0; i < 4; ++i) gload_lds16(kp + kg_off[i], &sK[cur ^ 1][kl_off[i]]);
                const u16* src = Vr + kvbase + (size_t)(k0 + KVB + vkey) * HD_ + vd0;
#pragma unroll
                for (int c = 0; c < 4; ++c) vn[c] = *(const u16x8*)(src + c * 8);
            }

            // QK^T -> 4 fragments of 16q x 16k
            f32x4 sf[4];
#pragma unroll
            for (int kt2 = 0; kt2 < 4; ++kt2) {
                f32x4 f = (f32x4){0.f, 0.f, 0.f, 0.f};
#pragma unroll
                for (int c = 0; c < 4; ++c) {
                    int key = kt2 * 16 + l15;
                    int addr = (key * 256 + c * 64 + l4 * 16) ^ ((key & 7) << 4);
                    bf16x8 kf = *(const bf16x8*)((const char*)sK[cur] + addr);
                    f = __builtin_amdgcn_mfma_f32_16x16x32_bf16(qf[c], kf, f, 0, 0, 0);
                }
                sf[kt2] = f;
            }
            // scale + causal mask + local row max
            float pm[4];
#pragma unroll
            for (int i = 0; i < 4; ++i) pm[i] = -1e30f;
#pragma unroll
            for (int kt2 = 0; kt2 < 4; ++kt2) {
                int kk = k0 + kt2 * 16 + l15;
#pragma unroll
                for (int i = 0; i < 4; ++i) {
                    int qq = qr0 + l4 * 4 + i;
                    float v = sf[kt2][i] * scale;
                    v = (kk <= qq) ? v : -1e30f;
                    sf[kt2][i] = v;
                    pm[i] = fmaxf(pm[i], v);
                }
            }
            // defer-max: full rescale path only when some row grew past mrow+8
            int need = 0;
#pragma unroll
            for (int i = 0; i < 4; ++i) need |= (pm[i] > mrow[i] + 8.f) ? 1 : 0;
            if (__any(need)) {
#pragma unroll
                for (int off = 1; off < 16; off <<= 1)
#pragma unroll
                    for (int i = 0; i < 4; ++i) pm[i] = fmaxf(pm[i], __shfl_xor(pm[i], off));
#pragma unroll
                for (int i = 0; i < 4; ++i) {
                    float mn = fmaxf(mrow[i], pm[i]);
                    float al = __expf(mrow[i] - mn);
                    mrow[i] = mn;
                    lsum[i] *= al;
#pragma unroll
                    for (int c2 = 0; c2 < 8; ++c2) oa[c2][i] *= al;
                }
            }
#pragma unroll
            for (int kt2 = 0; kt2 < 4; ++kt2)
#pragma unroll
                for (int i = 0; i < 4; ++i) sf[kt2][i] = __expf(sf[kt2][i] - mrow[i]);
#pragma unroll
            for (int i = 0; i < 4; ++i)
                lsum[i] += (sf[0][i] + sf[1][i]) + (sf[2][i] + sf[3][i]);

            // PV in two 32-key passes through per-wave sP
#pragma unroll
            for (int p = 0; p < 2; ++p) {
#pragma unroll
                for (int k2 = 0; k2 < 2; ++k2)
#pragma unroll
                    for (int i = 0; i < 4; ++i)
                        sP[w][(l4 * 4 + i) * SP_STRIDE + k2 * 16 + l15] = f2bf(sf[2 * p + k2][i]);
                bf16x8 paf = *(const bf16x8*)&sP[w][l15 * SP_STRIDE + l4 * 8];
#pragma unroll
                for (int c2 = 0; c2 < 8; ++c2) {
                    bf16x8 vf = *(const bf16x8*)&sVt[cur][(c2 * 16 + l15) * VT_STRIDE + p * 32 + l4 * 8];
                    oa[c2] = __builtin_amdgcn_mfma_f32_16x16x32_bf16(paf, vf, oa[c2], 0, 0, 0);
                }
            }

            if (pre) {
#pragma unroll
                for (int c = 0; c < 4; ++c)
#pragma unroll
                    for (int j = 0; j < 8; ++j)
                        sVt[cur ^ 1][(vd0 + c * 8 + j) * VT_STRIDE + vkey] = vn[c][j];
            }
            __syncthreads();
        }

        // epilogue: reduce lsum across the row group, divide, store
#pragma unroll
        for (int off = 1; off < 16; off <<= 1)
#pragma unroll
            for (int i = 0; i < 4; ++i) lsum[i] += __shfl_xor(lsum[i], off);
#pragma unroll
        for (int i = 0; i < 4; ++i) {
            float inv = 1.0f / lsum[i];
            int qrow = qr0 + l4 * 4 + i;
            size_t rbase = ((size_t)(b * S_LEN) + qrow) * (size_t)(NH_ * HD_) + h * HD_;
#pragma unroll
            for (int c2 = 0; c2 < 8; ++c2)
                Ao[rbase + c2 * 16 + l15] = f2bf(oa[c2][i] * inv);
        }
    }
}

// ---------------- launch ----------------
extern "C" void kernel_launch(void* const* d_in, const int* in_sizes, int n_in,
                              void* d_out, int out_size, void* d_ws, size_t ws_size,
                              hipStream_t stream) {
    (void)in_sizes; (void)n_in; (void)out_size; (void)ws_size;
    const float* hs  = (const float*)d_in[0];
    const int*   pos = (const int*)d_in[1];
    const float* q_w = (const float*)d_in[2];
    const float* q_b = (const float*)d_in[3];
    const float* k_w = (const float*)d_in[4];
    const float* k_b = (const float*)d_in[5];
    const float* v_w = (const float*)d_in[6];
    const float* v_b = (const float*)d_in[7];
    const float* o_w = (const float*)d_in[8];
    float* out = (float*)d_out;

    char* ws = (char*)d_ws;
    u16* hsb = (u16*)ws;   ws += (size_t)M_ROWS * HDIM * 2;
    u16* wcat = (u16*)ws;  ws += (size_t)NQKV * HDIM * 2;
    u16* owb = (u16*)ws;   ws += (size_t)HDIM * HDIM * 2;
    float* bcat = (float*)ws; ws += (size_t)NQKV * 4;
    float* tc = (float*)ws;   ws += (size_t)S_LEN * 64 * 4;
    float* ts = (float*)ws;   ws += (size_t)S_LEN * 64 * 4;
    u16* qkv = (u16*)ws;   ws += (size_t)M_ROWS * NQKV * 2;
    u16* Kr = (u16*)ws;    ws += (size_t)B_SZ * NKV_ * S_LEN * HD_ * 2;
    u16* Vr = (u16*)ws;    ws += (size_t)B_SZ * NKV_ * S_LEN * HD_ * 2;
    u16* Qr = hsb;   // alias: hsb dead after QKV GEMM
    u16* Ao = qkv;   // alias: qkv dead after rope_apply

    cvt_f32_bf16<<<(M_ROWS * HDIM / 4 + 255) / 256, 256, 0, stream>>>(hs, hsb, M_ROWS * HDIM / 4);
    cvt_f32_bf16<<<(2048 * 2048 / 4 + 255) / 256, 256, 0, stream>>>(q_w, wcat, 2048 * 2048 / 4);
    cvt_f32_bf16<<<(256 * 2048 / 4 + 255) / 256, 256, 0, stream>>>(k_w, wcat + (size_t)2048 * 2048, 256 * 2048 / 4);
    cvt_f32_bf16<<<(256 * 2048 / 4 + 255) / 256, 256, 0, stream>>>(v_w, wcat + (size_t)2304 * 2048, 256 * 2048 / 4);
    cvt_f32_bf16<<<(2048 * 2048 / 4 + 255) / 256, 256, 0, stream>>>(o_w, owb, 2048 * 2048 / 4);
    concat_bias<<<(NQKV + 255) / 256, 256, 0, stream>>>(q_b, k_b, v_b, bcat);
    rope_table<<<S_LEN, 64, 0, stream>>>(tc, ts);

    gemm_bt<u16, true><<<dim3(NQKV / 128, M_ROWS / 128), 256, 0, stream>>>(
        hsb, wcat, bcat, qkv, M_ROWS, NQKV, HDIM);

    rope_apply<<<(M_ROWS * 20 * 64 + 255) / 256, 256, 0, stream>>>(qkv, pos, tc, ts, Qr, Kr, Vr);

    attn_kernel<<<dim3(16, B_SZ * NH_), 256, 0, stream>>>(Qr, Kr, Vr, Ao);

    gemm_bt<float, false><<<dim3(HDIM / 128, M_ROWS / 128), 256, 0, stream>>>(
        Ao, owb, nullptr, out, M_ROWS, HDIM, HDIM);
}

// Round 6
// 350.808 us; speedup vs baseline: 1.1661x; 1.1661x over previous
//
#include <hip/hip_runtime.h>
#include <stdint.h>

typedef unsigned short u16;
typedef float    f32x4  __attribute__((ext_vector_type(4)));
typedef __bf16   bf16x8 __attribute__((ext_vector_type(8)));
typedef u16      u16x8  __attribute__((ext_vector_type(8)));
typedef u16      u16x4  __attribute__((ext_vector_type(4)));
typedef float    f32x4v __attribute__((ext_vector_type(4)));

#define B_SZ   2
#define S_LEN  2048
#define HDIM   2048
#define NH_    16
#define NKV_   2
#define HD_    128
#define M_ROWS 4096   // B*S
#define NQKV   2560   // (NH + 2*NKV) * HD

static __device__ __forceinline__ u16 f2bf(float f) {
    uint32_t u = __builtin_bit_cast(uint32_t, f);
    uint32_t r = (u + 0x7fffu + ((u >> 16) & 1u)) >> 16;
    return (u16)r;
}
static __device__ __forceinline__ float bf2f(u16 b) {
    uint32_t u = ((uint32_t)b) << 16;
    return __builtin_bit_cast(float, u);
}
static __device__ __forceinline__ void gload_lds16(const void* g, void* l) {
    __builtin_amdgcn_global_load_lds((__attribute__((address_space(1))) void*)(g),
                                     (__attribute__((address_space(3))) void*)(l),
                                     16, 0, 0);
}

// ---------------- elementwise converts ----------------
__global__ void cvt_f32_bf16(const float* __restrict__ in, u16* __restrict__ out, int n4) {
    int i = blockIdx.x * blockDim.x + threadIdx.x;
    if (i >= n4) return;
    f32x4v v = ((const f32x4v*)in)[i];
    u16x4 o;
    o[0] = f2bf(v[0]); o[1] = f2bf(v[1]); o[2] = f2bf(v[2]); o[3] = f2bf(v[3]);
    ((u16x4*)out)[i] = o;
}

__global__ void concat_bias(const float* __restrict__ qb, const float* __restrict__ kb,
                            const float* __restrict__ vb, float* __restrict__ out) {
    int i = blockIdx.x * blockDim.x + threadIdx.x;
    if (i >= NQKV) return;
    if (i < 2048)       out[i] = qb[i];
    else if (i < 2304)  out[i] = kb[i - 2048];
    else                out[i] = vb[i - 2304];
}

__global__ void rope_table(float* __restrict__ tc, float* __restrict__ ts) {
    int p = blockIdx.x;
    int d = threadIdx.x;   // 64 threads
    float inv = expf(-(float)d * 0.14391156831212787f);
    float ang = (float)p * inv;
    float s, c;
    sincosf(ang, &s, &c);
    tc[p * 64 + d] = c;
    ts[p * 64 + d] = s;
}

// ---------------- GEMM: C[m,n] = sum_k A[m,k]*W[n,k] (+bias[n]) ----------------
template <typename OutT, bool HAS_BIAS>
__global__ __launch_bounds__(256) void gemm_bt(const u16* __restrict__ A,
                                               const u16* __restrict__ W,
                                               const float* __restrict__ bias,
                                               OutT* __restrict__ C,
                                               int M, int N, int K) {
    __shared__ u16 sA[128 * 32];
    __shared__ u16 sB[128 * 32];
    const int tid = threadIdx.x;
    const int lane = tid & 63;
    const int w = tid >> 6;
    const int wr = w >> 1, wc = w & 1;
    const int l15 = lane & 15, l4 = lane >> 4;
    const int brow = blockIdx.y * 128;
    const int bcol = blockIdx.x * 128;

    f32x4 acc[4][4];
#pragma unroll
    for (int m = 0; m < 4; ++m)
#pragma unroll
        for (int n = 0; n < 4; ++n) acc[m][n] = (f32x4){0.f, 0.f, 0.f, 0.f};

    const int nk = K >> 5;
    for (int kt = 0; kt < nk; ++kt) {
        __syncthreads();
#pragma unroll
        for (int i = 0; i < 2; ++i) {
            int e = i * 2048 + tid * 8;
            int row = e >> 5, col = e & 31;
            gload_lds16(A + (size_t)(brow + row) * K + kt * 32 + col, &sA[e]);
            gload_lds16(W + (size_t)(bcol + row) * K + kt * 32 + col, &sB[e]);
        }
        __syncthreads();
        bf16x8 af[4], bfr[4];
#pragma unroll
        for (int m = 0; m < 4; ++m)
            af[m] = *(const bf16x8*)&sA[(wr * 64 + m * 16 + l15) * 32 + l4 * 8];
#pragma unroll
        for (int n = 0; n < 4; ++n)
            bfr[n] = *(const bf16x8*)&sB[(wc * 64 + n * 16 + l15) * 32 + l4 * 8];
#pragma unroll
        for (int m = 0; m < 4; ++m)
#pragma unroll
            for (int n = 0; n < 4; ++n)
                acc[m][n] = __builtin_amdgcn_mfma_f32_16x16x32_bf16(af[m], bfr[n], acc[m][n], 0, 0, 0);
    }

#pragma unroll
    for (int m = 0; m < 4; ++m) {
#pragma unroll
        for (int n = 0; n < 4; ++n) {
            int cn = bcol + wc * 64 + n * 16 + l15;
            float bv = 0.f;
            if constexpr (HAS_BIAS) bv = bias[cn];
#pragma unroll
            for (int i = 0; i < 4; ++i) {
                int r = brow + wr * 64 + m * 16 + l4 * 4 + i;
                float v = acc[m][n][i] + bv;
                if constexpr (sizeof(OutT) == 2) {
                    C[(size_t)r * N + cn] = (OutT)f2bf(v);
                } else {
                    C[(size_t)r * N + cn] = v;
                }
            }
        }
    }
}

// ---------------- RoPE + layout ----------------
__global__ void rope_apply(const u16* __restrict__ qkv, const int* __restrict__ pos,
                           const float* __restrict__ tc, const float* __restrict__ ts,
                           u16* __restrict__ Qr, u16* __restrict__ Kr, u16* __restrict__ Vr) {
    int idx = blockIdx.x * blockDim.x + threadIdx.x;
    if (idx >= M_ROWS * 20 * 64) return;
    int d = idx & 63;
    int sec = (idx >> 6) % 20;
    int row = idx / (20 * 64);
    int b = row >> 11, s = row & 2047;
    int p = pos[row];
    const u16* q = qkv + (size_t)row * NQKV;
    if (sec < 16) {
        float c = tc[p * 64 + d], sn = ts[p * 64 + d];
        float x1 = bf2f(q[sec * 128 + d]);
        float x2 = bf2f(q[sec * 128 + d + 64]);
        size_t o = (((size_t)(b * NH_ + sec)) * S_LEN + s) * HD_ + d;
        Qr[o] = f2bf(x1 * c - x2 * sn);
        Qr[o + 64] = f2bf(x2 * c + x1 * sn);
    } else if (sec < 18) {
        int hk = sec - 16;
        float c = tc[p * 64 + d], sn = ts[p * 64 + d];
        float x1 = bf2f(q[2048 + hk * 128 + d]);
        float x2 = bf2f(q[2048 + hk * 128 + d + 64]);
        size_t o = (((size_t)(b * NKV_ + hk)) * S_LEN + s) * HD_ + d;
        Kr[o] = f2bf(x1 * c - x2 * sn);
        Kr[o + 64] = f2bf(x2 * c + x1 * sn);
    } else {
        int hv = sec - 18;
        size_t o = (((size_t)(b * NKV_ + hv)) * S_LEN + s) * HD_ + d;
        Vr[o] = q[2304 + hv * 128 + d];
        Vr[o + 64] = q[2304 + hv * 128 + d + 64];
    }
}

// ---------------- flash attention (causal, GQA) ----------------
// grid: (8, B*NH), 512 threads = 8 waves (2 waves/SIMD at 1 block/CU).
// Each block: q-tiles {x, 15-x} of 128 rows (uniform 34 KV-tiles of 64).
// 16 q-rows/wave. Double-buffered, 1 barrier/tile, defer-max softmax.
#define QB 128
#define KVB 64
#define VT_STRIDE 72   // 144B rows: 16B-aligned b128 reads, even bank-quad spread
#define SP_STRIDE 40   // 80B rows
__global__ __launch_bounds__(512, 2) void attn_kernel(const u16* __restrict__ Qr,
                                                      const u16* __restrict__ Kr,
                                                      const u16* __restrict__ Vr,
                                                      u16* __restrict__ Ao) {
    __shared__ u16 sK[2][KVB * HD_];         // XOR-swizzled rows [key][d]  (2x16KB)
    __shared__ u16 sVt[2][HD_ * VT_STRIDE];  // transposed [d][key]         (2x18KB)
    __shared__ u16 sP[8][16 * SP_STRIDE];    // per-wave P tile (10KB)

    const int tid = threadIdx.x;
    const int lane = tid & 63;
    const int w = tid >> 6;
    const int l15 = lane & 15;
    const int l4 = lane >> 4;

    const int bh = blockIdx.y;
    const int b = bh >> 4;
    const int h = bh & 15;
    const int kvh = h >> 3;
    const size_t kvbase = ((size_t)(b * NKV_ + kvh)) * S_LEN * HD_;

    // K staging mapping (pre-swizzled global source, linear LDS dest)
    // 64 rows x 128 u16 = 8192 elems; 512 threads x 8 elems x 2 iters
    int kg_off[2], kl_off[2];
#pragma unroll
    for (int i = 0; i < 2; ++i) {
        int e = i * 4096 + tid * 8;
        int L = e * 2;
        int key = L >> 8;
        int inner = (L & 255) ^ ((key & 7) << 4);
        kg_off[i] = key * HD_ + (inner >> 1);
        kl_off[i] = e;
    }
    // V staging mapping: thread -> (key, 16-d chunk)
    const int vkey = tid & 63;
    const int vd0 = (tid >> 6) * 16;

    const float scale = 0.08838834764831845f;  // 1/sqrt(128)

    for (int pass = 0; pass < 2; ++pass) {
        const int qbk = pass ? (15 - blockIdx.x) : blockIdx.x;
        const int qr0 = qbk * QB + w * 16;
        const size_t qbase = (((size_t)(b * NH_ + h)) * S_LEN + qr0 + l15) * HD_;
        bf16x8 qf[4];
#pragma unroll
        for (int c = 0; c < 4; ++c)
            qf[c] = *(const bf16x8*)(Qr + qbase + c * 32 + l4 * 8);

        f32x4 oa[8];
#pragma unroll
        for (int c = 0; c < 8; ++c) oa[c] = (f32x4){0.f, 0.f, 0.f, 0.f};
        float mrow[4], lsum[4];
#pragma unroll
        for (int i = 0; i < 4; ++i) { mrow[i] = -1e30f; lsum[i] = 0.f; }

        const int nt = 2 * qbk + 2;

        // ---- prologue: stage tile 0 into buffer 0 ----
        {
            const u16* kp = Kr + kvbase;
#pragma unroll
            for (int i = 0; i < 2; ++i) gload_lds16(kp + kg_off[i], &sK[0][kl_off[i]]);
            const u16* src = Vr + kvbase + (size_t)vkey * HD_ + vd0;
            u16x8 v0[2];
#pragma unroll
            for (int c = 0; c < 2; ++c) v0[c] = *(const u16x8*)(src + c * 8);
#pragma unroll
            for (int c = 0; c < 2; ++c)
#pragma unroll
                for (int j = 0; j < 8; ++j)
                    sVt[0][(vd0 + c * 8 + j) * VT_STRIDE + vkey] = v0[c][j];
        }
        __syncthreads();

        for (int t = 0; t < nt; ++t) {
            const int cur = t & 1;
            const int k0 = t * KVB;
            u16x8 vn[2];
            const bool pre = (t + 1 < nt);
            if (pre) {
                const u16* kp = Kr + kvbase + (size_t)(k0 + KVB) * HD_;
#pragma unroll
                for (int i = 0; i < 2; ++i) gload_lds16(kp + kg_off[i], &sK[cur ^ 1][kl_off[i]]);
                const u16* src = Vr + kvbase + (size_t)(k0 + KVB + vkey) * HD_ + vd0;
#pragma unroll
                for (int c = 0; c < 2; ++c) vn[c] = *(const u16x8*)(src + c * 8);
            }

            if (k0 <= qr0 + 15) {   // wave-uniform causal skip of fully-masked tiles
                // QK^T -> 4 fragments of 16q x 16k
                f32x4 sf[4];
                __builtin_amdgcn_s_setprio(1);
#pragma unroll
                for (int kt2 = 0; kt2 < 4; ++kt2) {
                    f32x4 f = (f32x4){0.f, 0.f, 0.f, 0.f};
#pragma unroll
                    for (int c = 0; c < 4; ++c) {
                        int key = kt2 * 16 + l15;
                        int addr = (key * 256 + c * 64 + l4 * 16) ^ ((key & 7) << 4);
                        bf16x8 kf = *(const bf16x8*)((const char*)sK[cur] + addr);
                        f = __builtin_amdgcn_mfma_f32_16x16x32_bf16(qf[c], kf, f, 0, 0, 0);
                    }
                    sf[kt2] = f;
                }
                __builtin_amdgcn_s_setprio(0);
                // scale + causal mask + local row max
                float pm[4];
#pragma unroll
                for (int i = 0; i < 4; ++i) pm[i] = -1e30f;
#pragma unroll
                for (int kt2 = 0; kt2 < 4; ++kt2) {
                    int kk = k0 + kt2 * 16 + l15;
#pragma unroll
                    for (int i = 0; i < 4; ++i) {
                        int qq = qr0 + l4 * 4 + i;
                        float v = sf[kt2][i] * scale;
                        v = (kk <= qq) ? v : -1e30f;
                        sf[kt2][i] = v;
                        pm[i] = fmaxf(pm[i], v);
                    }
                }
                // defer-max: full rescale path only when some row grew past mrow+8
                int need = 0;
#pragma unroll
                for (int i = 0; i < 4; ++i) need |= (pm[i] > mrow[i] + 8.f) ? 1 : 0;
                if (__any(need)) {
#pragma unroll
                    for (int off = 1; off < 16; off <<= 1)
#pragma unroll
                        for (int i = 0; i < 4; ++i) pm[i] = fmaxf(pm[i], __shfl_xor(pm[i], off));
#pragma unroll
                    for (int i = 0; i < 4; ++i) {
                        float mn = fmaxf(mrow[i], pm[i]);
                        float al = __expf(mrow[i] - mn);
                        mrow[i] = mn;
                        lsum[i] *= al;
#pragma unroll
                        for (int c2 = 0; c2 < 8; ++c2) oa[c2][i] *= al;
                    }
                }
#pragma unroll
                for (int kt2 = 0; kt2 < 4; ++kt2)
#pragma unroll
                    for (int i = 0; i < 4; ++i) sf[kt2][i] = __expf(sf[kt2][i] - mrow[i]);
#pragma unroll
                for (int i = 0; i < 4; ++i)
                    lsum[i] += (sf[0][i] + sf[1][i]) + (sf[2][i] + sf[3][i]);

                // PV in two 32-key passes through per-wave sP
#pragma unroll
                for (int p = 0; p < 2; ++p) {
#pragma unroll
                    for (int k2 = 0; k2 < 2; ++k2)
#pragma unroll
                        for (int i = 0; i < 4; ++i)
                            sP[w][(l4 * 4 + i) * SP_STRIDE + k2 * 16 + l15] = f2bf(sf[2 * p + k2][i]);
                    bf16x8 paf = *(const bf16x8*)&sP[w][l15 * SP_STRIDE + l4 * 8];
                    __builtin_amdgcn_s_setprio(1);
#pragma unroll
                    for (int c2 = 0; c2 < 8; ++c2) {
                        bf16x8 vf = *(const bf16x8*)&sVt[cur][(c2 * 16 + l15) * VT_STRIDE + p * 32 + l4 * 8];
                        oa[c2] = __builtin_amdgcn_mfma_f32_16x16x32_bf16(paf, vf, oa[c2], 0, 0, 0);
                    }
                    __builtin_amdgcn_s_setprio(0);
                }
            }

            if (pre) {
#pragma unroll
                for (int c = 0; c < 2; ++c)
#pragma unroll
                    for (int j = 0; j < 8; ++j)
                        sVt[cur ^ 1][(vd0 + c * 8 + j) * VT_STRIDE + vkey] = vn[c][j];
            }
            __syncthreads();
        }

        // epilogue: reduce lsum across the row group, divide, store
#pragma unroll
        for (int off = 1; off < 16; off <<= 1)
#pragma unroll
            for (int i = 0; i < 4; ++i) lsum[i] += __shfl_xor(lsum[i], off);
#pragma unroll
        for (int i = 0; i < 4; ++i) {
            float inv = 1.0f / lsum[i];
            int qrow = qr0 + l4 * 4 + i;
            size_t rbase = ((size_t)(b * S_LEN) + qrow) * (size_t)(NH_ * HD_) + h * HD_;
#pragma unroll
            for (int c2 = 0; c2 < 8; ++c2)
                Ao[rbase + c2 * 16 + l15] = f2bf(oa[c2][i] * inv);
        }
    }
}

// ---------------- launch ----------------
extern "C" void kernel_launch(void* const* d_in, const int* in_sizes, int n_in,
                              void* d_out, int out_size, void* d_ws, size_t ws_size,
                              hipStream_t stream) {
    (void)in_sizes; (void)n_in; (void)out_size; (void)ws_size;
    const float* hs  = (const float*)d_in[0];
    const int*   pos = (const int*)d_in[1];
    const float* q_w = (const float*)d_in[2];
    const float* q_b = (const float*)d_in[3];
    const float* k_w = (const float*)d_in[4];
    const float* k_b = (const float*)d_in[5];
    const float* v_w = (const float*)d_in[6];
    const float* v_b = (const float*)d_in[7];
    const float* o_w = (const float*)d_in[8];
    float* out = (float*)d_out;

    char* ws = (char*)d_ws;
    u16* hsb = (u16*)ws;   ws += (size_t)M_ROWS * HDIM * 2;
    u16* wcat = (u16*)ws;  ws += (size_t)NQKV * HDIM * 2;
    u16* owb = (u16*)ws;   ws += (size_t)HDIM * HDIM * 2;
    float* bcat = (float*)ws; ws += (size_t)NQKV * 4;
    float* tc = (float*)ws;   ws += (size_t)S_LEN * 64 * 4;
    float* ts = (float*)ws;   ws += (size_t)S_LEN * 64 * 4;
    u16* qkv = (u16*)ws;   ws += (size_t)M_ROWS * NQKV * 2;
    u16* Kr = (u16*)ws;    ws += (size_t)B_SZ * NKV_ * S_LEN * HD_ * 2;
    u16* Vr = (u16*)ws;    ws += (size_t)B_SZ * NKV_ * S_LEN * HD_ * 2;
    u16* Qr = hsb;   // alias: hsb dead after QKV GEMM
    u16* Ao = qkv;   // alias: qkv dead after rope_apply

    cvt_f32_bf16<<<(M_ROWS * HDIM / 4 + 255) / 256, 256, 0, stream>>>(hs, hsb, M_ROWS * HDIM / 4);
    cvt_f32_bf16<<<(2048 * 2048 / 4 + 255) / 256, 256, 0, stream>>>(q_w, wcat, 2048 * 2048 / 4);
    cvt_f32_bf16<<<(256 * 2048 / 4 + 255) / 256, 256, 0, stream>>>(k_w, wcat + (size_t)2048 * 2048, 256 * 2048 / 4);
    cvt_f32_bf16<<<(256 * 2048 / 4 + 255) / 256, 256, 0, stream>>>(v_w, wcat + (size_t)2304 * 2048, 256 * 2048 / 4);
    cvt_f32_bf16<<<(2048 * 2048 / 4 + 255) / 256, 256, 0, stream>>>(o_w, owb, 2048 * 2048 / 4);
    concat_bias<<<(NQKV + 255) / 256, 256, 0, stream>>>(q_b, k_b, v_b, bcat);
    rope_table<<<S_LEN, 64, 0, stream>>>(tc, ts);

    gemm_bt<u16, true><<<dim3(NQKV / 128, M_ROWS / 128), 256, 0, stream>>>(
        hsb, wcat, bcat, qkv, M_ROWS, NQKV, HDIM);

    rope_apply<<<(M_ROWS * 20 * 64 + 255) / 256, 256, 0, stream>>>(qkv, pos, tc, ts, Qr, Kr, Vr);

    attn_kernel<<<dim3(8, B_SZ * NH_), 512, 0, stream>>>(Qr, Kr, Vr, Ao);

    gemm_bt<float, false><<<dim3(HDIM / 128, M_ROWS / 128), 256, 0, stream>>>(
        Ao, owb, nullptr, out, M_ROWS, HDIM, HDIM);
}

// Round 10
// 347.174 us; speedup vs baseline: 1.1784x; 1.0105x over previous
//
#include <hip/hip_runtime.h>
#include <stdint.h>

typedef unsigned short u16;
typedef float    f32x4  __attribute__((ext_vector_type(4)));
typedef __bf16   bf16x8 __attribute__((ext_vector_type(8)));
typedef u16      u16x8  __attribute__((ext_vector_type(8)));
typedef u16      u16x4  __attribute__((ext_vector_type(4)));
typedef float    f32x4v __attribute__((ext_vector_type(4)));

#define B_SZ   2
#define S_LEN  2048
#define HDIM   2048
#define NH_    16
#define NKV_   2
#define HD_    128
#define M_ROWS 4096   // B*S
#define NQKV   2560   // (NH + 2*NKV) * HD

static __device__ __forceinline__ u16 f2bf(float f) {
    uint32_t u = __builtin_bit_cast(uint32_t, f);
    uint32_t r = (u + 0x7fffu + ((u >> 16) & 1u)) >> 16;
    return (u16)r;
}
static __device__ __forceinline__ float bf2f(u16 b) {
    uint32_t u = ((uint32_t)b) << 16;
    return __builtin_bit_cast(float, u);
}
static __device__ __forceinline__ void gload_lds16(const void* g, void* l) {
    __builtin_amdgcn_global_load_lds((__attribute__((address_space(1))) void*)(g),
                                     (__attribute__((address_space(3))) void*)(l),
                                     16, 0, 0);
}

// ---------------- elementwise converts ----------------
__global__ void cvt_f32_bf16(const float* __restrict__ in, u16* __restrict__ out, int n4) {
    int i = blockIdx.x * blockDim.x + threadIdx.x;
    if (i >= n4) return;
    f32x4v v = ((const f32x4v*)in)[i];
    u16x4 o;
    o[0] = f2bf(v[0]); o[1] = f2bf(v[1]); o[2] = f2bf(v[2]); o[3] = f2bf(v[3]);
    ((u16x4*)out)[i] = o;
}

__global__ void concat_bias(const float* __restrict__ qb, const float* __restrict__ kb,
                            const float* __restrict__ vb, float* __restrict__ out) {
    int i = blockIdx.x * blockDim.x + threadIdx.x;
    if (i >= NQKV) return;
    if (i < 2048)       out[i] = qb[i];
    else if (i < 2304)  out[i] = kb[i - 2048];
    else                out[i] = vb[i - 2304];
}

__global__ void rope_table(float* __restrict__ tc, float* __restrict__ ts) {
    int p = blockIdx.x;
    int d = threadIdx.x;   // 64 threads
    float inv = expf(-(float)d * 0.14391156831212787f);
    float ang = (float)p * inv;
    float s, c;
    sincosf(ang, &s, &c);
    tc[p * 64 + d] = c;
    ts[p * 64 + d] = s;
}

// ---------------- GEMM 256x256, BK=64, 8 waves, phase-pipelined ----------------
// C[m,n] = sum_k A[m,k]*W[n,k] (+bias[n]).  Counted-vmcnt schedule:
//   per K-tile T (4 phases): q0/q1 stage A-halves of T+1, q2/q3 stage B-halves of T+2;
//   vmcnt(4) once per tile-end confirms A(T+1)+B(T+1), leaves B(T+2) in flight.
template <typename OutT, bool HAS_BIAS>
__global__ __launch_bounds__(512, 2) void gemm256(const u16* __restrict__ A,
                                                  const u16* __restrict__ W,
                                                  const float* __restrict__ bias,
                                                  OutT* __restrict__ C,
                                                  int M, int N, int K) {
    __shared__ u16 sA[2][256 * 64];   // 64 KiB
    __shared__ u16 sB[2][256 * 64];   // 64 KiB
    const int tid = threadIdx.x;
    const int lane = tid & 63;
    const int w = tid >> 6;       // 0..7
    const int wr = w >> 2;        // 0..1 (M half)
    const int wc = w & 3;         // 0..3 (N quarter)
    const int l15 = lane & 15, l4 = lane >> 4;
    const int brow = blockIdx.y * 256;
    const int bcol = blockIdx.x * 256;
    const int NT = K >> 6;

    // staging map: thread covers 2x16B per 16KiB half-tile; linear LDS dest,
    // pre-swizzled global source (read-side XOR (row&7)<<4 on byte col)
    int st_row[2], st_col[2];
#pragma unroll
    for (int j = 0; j < 2; ++j) {
        int D = j * 8192 + tid * 16;   // dest byte within half-tile
        int row = D >> 7;              // 0..127
        int Y = D & 127;
        st_row[j] = row;
        st_col[j] = (Y ^ ((row & 7) << 4)) >> 1;  // source col (u16 elems)
    }

#define STAGE_HALF(lds, G, row0, h, kt)                                               \
    do {                                                                              \
        _Pragma("unroll")                                                             \
        for (int j = 0; j < 2; ++j) {                                                 \
            const u16* gs = (G) + (size_t)((row0) + (h) * 128 + st_row[j]) * K +      \
                            (kt) * 64 + st_col[j];                                    \
            gload_lds16(gs, (lds) + (h) * 8192 + j * 4096 + tid * 8);                 \
        }                                                                             \
    } while (0)

    f32x4 acc[8][4];
#pragma unroll
    for (int m = 0; m < 8; ++m)
#pragma unroll
        for (int n = 0; n < 4; ++n) acc[m][n] = (f32x4){0.f, 0.f, 0.f, 0.f};

    const int swz = (l15 & 7) << 4;
    const int cb0 = (l4 * 16) ^ swz;        // kslice 0 byte col
    const int cb1 = (64 + l4 * 16) ^ swz;   // kslice 1 byte col

    // ---- prologue: B(T0) h0,h1 ; A(T0) h0,h1 ; B(T1) h0,h1 ----
    STAGE_HALF(sB[0], W, bcol, 0, 0);
    STAGE_HALF(sB[0], W, bcol, 1, 0);
    STAGE_HALF(sA[0], A, brow, 0, 0);
    STAGE_HALF(sA[0], A, brow, 1, 0);
    if (NT > 1) {
        STAGE_HALF(sB[1], W, bcol, 0, 1);
        STAGE_HALF(sB[1], W, bcol, 1, 1);
        asm volatile("s_waitcnt vmcnt(4)" ::: "memory");  // B(T0),A(T0) landed
    } else {
        asm volatile("s_waitcnt vmcnt(0)" ::: "memory");
    }
    __builtin_amdgcn_sched_barrier(0);
    __builtin_amdgcn_s_barrier();

    for (int T = 0; T < NT; ++T) {
        const int cur = T & 1;
        const u16* curA = sA[cur];
        const u16* curB = sB[cur];
        u16* nxtA = sA[cur ^ 1];
        u16* curBw = sB[cur];   // B(T+2) has same parity as T

        bf16x8 bfr[4][2];
#pragma unroll
        for (int q = 0; q < 4; ++q) {
            // ---- ds-load register subtile from buf[cur] ----
            if (q == 0) {
#pragma unroll
                for (int n = 0; n < 4; ++n) {
                    int row = wc * 64 + n * 16 + l15;
                    bfr[n][0] = *(const bf16x8*)((const char*)curB + row * 128 + cb0);
                    bfr[n][1] = *(const bf16x8*)((const char*)curB + row * 128 + cb1);
                }
            }
            bf16x8 af[2][2];
#pragma unroll
            for (int mm = 0; mm < 2; ++mm) {
                int row = wr * 128 + (q * 2 + mm) * 16 + l15;
                af[mm][0] = *(const bf16x8*)((const char*)curA + row * 128 + cb0);
                af[mm][1] = *(const bf16x8*)((const char*)curA + row * 128 + cb1);
            }
            // ---- stage 1 half-tile prefetch ----
            if (q == 0 && T + 1 < NT) STAGE_HALF(nxtA, A, brow, 0, T + 1);
            if (q == 1 && T + 1 < NT) STAGE_HALF(nxtA, A, brow, 1, T + 1);
            if (q == 2 && T + 2 < NT) STAGE_HALF(curBw, W, bcol, 0, T + 2);
            if (q == 3 && T + 2 < NT) STAGE_HALF(curBw, W, bcol, 1, T + 2);

            __builtin_amdgcn_s_barrier();
            __builtin_amdgcn_s_setprio(1);
#pragma unroll
            for (int mm = 0; mm < 2; ++mm)
#pragma unroll
                for (int n = 0; n < 4; ++n)
#pragma unroll
                    for (int s = 0; s < 2; ++s)
                        acc[q * 2 + mm][n] = __builtin_amdgcn_mfma_f32_16x16x32_bf16(
                            af[mm][s], bfr[n][s], acc[q * 2 + mm][n], 0, 0, 0);
            __builtin_amdgcn_s_setprio(0);
            if (q == 3) {
                // tile-end counted wait: confirm A(T+1)+B(T+1); leave B(T+2) in flight
                if (T + 2 < NT) {
                    asm volatile("s_waitcnt vmcnt(4)" ::: "memory");
                } else if (T + 2 == NT) {
                    asm volatile("s_waitcnt vmcnt(0)" ::: "memory");
                }
                __builtin_amdgcn_sched_barrier(0);
            }
            __builtin_amdgcn_s_barrier();
        }
    }
#undef STAGE_HALF

    // ---- epilogue ----
#pragma unroll
    for (int m = 0; m < 8; ++m) {
#pragma unroll
        for (int n = 0; n < 4; ++n) {
            int cn = bcol + wc * 64 + n * 16 + l15;
            float bv = 0.f;
            if constexpr (HAS_BIAS) bv = bias[cn];
#pragma unroll
            for (int i = 0; i < 4; ++i) {
                int r = brow + wr * 128 + m * 16 + l4 * 4 + i;
                float v = acc[m][n][i] + bv;
                if constexpr (sizeof(OutT) == 2) {
                    C[(size_t)r * N + cn] = (OutT)f2bf(v);
                } else {
                    C[(size_t)r * N + cn] = v;
                }
            }
        }
    }
}

// ---------------- RoPE + layout ----------------
__global__ void rope_apply(const u16* __restrict__ qkv, const int* __restrict__ pos,
                           const float* __restrict__ tc, const float* __restrict__ ts,
                           u16* __restrict__ Qr, u16* __restrict__ Kr, u16* __restrict__ Vr) {
    int idx = blockIdx.x * blockDim.x + threadIdx.x;
    if (idx >= M_ROWS * 20 * 64) return;
    int d = idx & 63;
    int sec = (idx >> 6) % 20;
    int row = idx / (20 * 64);
    int b = row >> 11, s = row & 2047;
    int p = pos[row];
    const u16* q = qkv + (size_t)row * NQKV;
    if (sec < 16) {
        float c = tc[p * 64 + d], sn = ts[p * 64 + d];
        float x1 = bf2f(q[sec * 128 + d]);
        float x2 = bf2f(q[sec * 128 + d + 64]);
        size_t o = (((size_t)(b * NH_ + sec)) * S_LEN + s) * HD_ + d;
        Qr[o] = f2bf(x1 * c - x2 * sn);
        Qr[o + 64] = f2bf(x2 * c + x1 * sn);
    } else if (sec < 18) {
        int hk = sec - 16;
        float c = tc[p * 64 + d], sn = ts[p * 64 + d];
        float x1 = bf2f(q[2048 + hk * 128 + d]);
        float x2 = bf2f(q[2048 + hk * 128 + d + 64]);
        size_t o = (((size_t)(b * NKV_ + hk)) * S_LEN + s) * HD_ + d;
        Kr[o] = f2bf(x1 * c - x2 * sn);
        Kr[o + 64] = f2bf(x2 * c + x1 * sn);
    } else {
        int hv = sec - 18;
        size_t o = (((size_t)(b * NKV_ + hv)) * S_LEN + s) * HD_ + d;
        Vr[o] = q[2304 + hv * 128 + d];
        Vr[o + 64] = q[2304 + hv * 128 + d + 64];
    }
}

// ---------------- flash attention (causal, GQA) ----------------
// grid: (8, B*NH), 512 threads = 8 waves (2 waves/SIMD at 1 block/CU).
// Each block: q-tiles {x, 15-x} of 128 rows (uniform 34 KV-tiles of 64).
// 16 q-rows/wave. Double-buffered, 1 barrier/tile, defer-max softmax.
#define QB 128
#define KVB 64
#define VT_STRIDE 72   // 144B rows: 16B-aligned b128 reads, even bank-quad spread
#define SP_STRIDE 40   // 80B rows
__global__ __launch_bounds__(512, 2) void attn_kernel(const u16* __restrict__ Qr,
                                                      const u16* __restrict__ Kr,
                                                      const u16* __restrict__ Vr,
                                                      u16* __restrict__ Ao) {
    __shared__ u16 sK[2][KVB * HD_];         // XOR-swizzled rows [key][d]  (2x16KB)
    __shared__ u16 sVt[2][HD_ * VT_STRIDE];  // transposed [d][key]         (2x18KB)
    __shared__ u16 sP[8][16 * SP_STRIDE];    // per-wave P tile (10KB)

    const int tid = threadIdx.x;
    const int lane = tid & 63;
    const int w = tid >> 6;
    const int l15 = lane & 15;
    const int l4 = lane >> 4;

    const int bh = blockIdx.y;
    const int b = bh >> 4;
    const int h = bh & 15;
    const int kvh = h >> 3;
    const size_t kvbase = ((size_t)(b * NKV_ + kvh)) * S_LEN * HD_;

    // K staging mapping (pre-swizzled global source, linear LDS dest)
    // 64 rows x 128 u16 = 8192 elems; 512 threads x 8 elems x 2 iters
    int kg_off[2], kl_off[2];
#pragma unroll
    for (int i = 0; i < 2; ++i) {
        int e = i * 4096 + tid * 8;
        int L = e * 2;
        int key = L >> 8;
        int inner = (L & 255) ^ ((key & 7) << 4);
        kg_off[i] = key * HD_ + (inner >> 1);
        kl_off[i] = e;
    }
    // V staging mapping: thread -> (key, 16-d chunk)
    const int vkey = tid & 63;
    const int vd0 = (tid >> 6) * 16;

    const float scale = 0.08838834764831845f;  // 1/sqrt(128)

    for (int pass = 0; pass < 2; ++pass) {
        const int qbk = pass ? (15 - blockIdx.x) : blockIdx.x;
        const int qr0 = qbk * QB + w * 16;
        const size_t qbase = (((size_t)(b * NH_ + h)) * S_LEN + qr0 + l15) * HD_;
        bf16x8 qf[4];
#pragma unroll
        for (int c = 0; c < 4; ++c)
            qf[c] = *(const bf16x8*)(Qr + qbase + c * 32 + l4 * 8);

        f32x4 oa[8];
#pragma unroll
        for (int c = 0; c < 8; ++c) oa[c] = (f32x4){0.f, 0.f, 0.f, 0.f};
        float mrow[4], lsum[4];
#pragma unroll
        for (int i = 0; i < 4; ++i) { mrow[i] = -1e30f; lsum[i] = 0.f; }

        const int nt = 2 * qbk + 2;

        // ---- prologue: stage tile 0 into buffer 0 ----
        {
            const u16* kp = Kr + kvbase;
#pragma unroll
            for (int i = 0; i < 2; ++i) gload_lds16(kp + kg_off[i], &sK[0][kl_off[i]]);
            const u16* src = Vr + kvbase + (size_t)vkey * HD_ + vd0;
            u16x8 v0[2];
#pragma unroll
            for (int c = 0; c < 2; ++c) v0[c] = *(const u16x8*)(src + c * 8);
#pragma unroll
            for (int c = 0; c < 2; ++c)
#pragma unroll
                for (int j = 0; j < 8; ++j)
                    sVt[0][(vd0 + c * 8 + j) * VT_STRIDE + vkey] = v0[c][j];
        }
        __syncthreads();

        for (int t = 0; t < nt; ++t) {
            const int cur = t & 1;
            const int k0 = t * KVB;
            u16x8 vn[2];
            const bool pre = (t + 1 < nt);
            if (pre) {
                const u16* kp = Kr + kvbase + (size_t)(k0 + KVB) * HD_;
#pragma unroll
                for (int i = 0; i < 2; ++i) gload_lds16(kp + kg_off[i], &sK[cur ^ 1][kl_off[i]]);
                const u16* src = Vr + kvbase + (size_t)(k0 + KVB + vkey) * HD_ + vd0;
#pragma unroll
                for (int c = 0; c < 2; ++c) vn[c] = *(const u16x8*)(src + c * 8);
            }

            if (k0 <= qr0 + 15) {   // wave-uniform causal skip of fully-masked tiles
                // QK^T -> 4 fragments of 16q x 16k
                f32x4 sf[4];
                __builtin_amdgcn_s_setprio(1);
#pragma unroll
                for (int kt2 = 0; kt2 < 4; ++kt2) {
                    f32x4 f = (f32x4){0.f, 0.f, 0.f, 0.f};
#pragma unroll
                    for (int c = 0; c < 4; ++c) {
                        int key = kt2 * 16 + l15;
                        int addr = (key * 256 + c * 64 + l4 * 16) ^ ((key & 7) << 4);
                        bf16x8 kf = *(const bf16x8*)((const char*)sK[cur] + addr);
                        f = __builtin_amdgcn_mfma_f32_16x16x32_bf16(qf[c], kf, f, 0, 0, 0);
                    }
                    sf[kt2] = f;
                }
                __builtin_amdgcn_s_setprio(0);
                // scale + causal mask + local row max
                float pm[4];
#pragma unroll
                for (int i = 0; i < 4; ++i) pm[i] = -1e30f;
#pragma unroll
                for (int kt2 = 0; kt2 < 4; ++kt2) {
                    int kk = k0 + kt2 * 16 + l15;
#pragma unroll
                    for (int i = 0; i < 4; ++i) {
                        int qq = qr0 + l4 * 4 + i;
                        float v = sf[kt2][i] * scale;
                        v = (kk <= qq) ? v : -1e30f;
                        sf[kt2][i] = v;
                        pm[i] = fmaxf(pm[i], v);
                    }
                }
                // defer-max: full rescale path only when some row grew past mrow+8
                int need = 0;
#pragma unroll
                for (int i = 0; i < 4; ++i) need |= (pm[i] > mrow[i] + 8.f) ? 1 : 0;
                if (__any(need)) {
#pragma unroll
                    for (int off = 1; off < 16; off <<= 1)
#pragma unroll
                        for (int i = 0; i < 4; ++i) pm[i] = fmaxf(pm[i], __shfl_xor(pm[i], off));
#pragma unroll
                    for (int i = 0; i < 4; ++i) {
                        float mn = fmaxf(mrow[i], pm[i]);
                        float al = __expf(mrow[i] - mn);
                        mrow[i] = mn;
                        lsum[i] *= al;
#pragma unroll
                        for (int c2 = 0; c2 < 8; ++c2) oa[c2][i] *= al;
                    }
                }
#pragma unroll
                for (int kt2 = 0; kt2 < 4; ++kt2)
#pragma unroll
                    for (int i = 0; i < 4; ++i) sf[kt2][i] = __expf(sf[kt2][i] - mrow[i]);
#pragma unroll
                for (int i = 0; i < 4; ++i)
                    lsum[i] += (sf[0][i] + sf[1][i]) + (sf[2][i] + sf[3][i]);

                // PV in two 32-key passes through per-wave sP
#pragma unroll
                for (int p = 0; p < 2; ++p) {
#pragma unroll
                    for (int k2 = 0; k2 < 2; ++k2)
#pragma unroll
                        for (int i = 0; i < 4; ++i)
                            sP[w][(l4 * 4 + i) * SP_STRIDE + k2 * 16 + l15] = f2bf(sf[2 * p + k2][i]);
                    bf16x8 paf = *(const bf16x8*)&sP[w][l15 * SP_STRIDE + l4 * 8];
                    __builtin_amdgcn_s_setprio(1);
#pragma unroll
                    for (int c2 = 0; c2 < 8; ++c2) {
                        bf16x8 vf = *(const bf16x8*)&sVt[cur][(c2 * 16 + l15) * VT_STRIDE + p * 32 + l4 * 8];
                        oa[c2] = __builtin_amdgcn_mfma_f32_16x16x32_bf16(paf, vf, oa[c2], 0, 0, 0);
                    }
                    __builtin_amdgcn_s_setprio(0);
                }
            }

            if (pre) {
#pragma unroll
                for (int c = 0; c < 2; ++c)
#pragma unroll
                    for (int j = 0; j < 8; ++j)
                        sVt[cur ^ 1][(vd0 + c * 8 + j) * VT_STRIDE + vkey] = vn[c][j];
            }
            __syncthreads();
        }

        // epilogue: reduce lsum across the row group, divide, store
#pragma unroll
        for (int off = 1; off < 16; off <<= 1)
#pragma unroll
            for (int i = 0; i < 4; ++i) lsum[i] += __shfl_xor(lsum[i], off);
#pragma unroll
        for (int i = 0; i < 4; ++i) {
            float inv = 1.0f / lsum[i];
            int qrow = qr0 + l4 * 4 + i;
            size_t rbase = ((size_t)(b * S_LEN) + qrow) * (size_t)(NH_ * HD_) + h * HD_;
#pragma unroll
            for (int c2 = 0; c2 < 8; ++c2)
                Ao[rbase + c2 * 16 + l15] = f2bf(oa[c2][i] * inv);
        }
    }
}

// ---------------- launch ----------------
extern "C" void kernel_launch(void* const* d_in, const int* in_sizes, int n_in,
                              void* d_out, int out_size, void* d_ws, size_t ws_size,
                              hipStream_t stream) {
    (void)in_sizes; (void)n_in; (void)out_size; (void)ws_size;
    const float* hs  = (const float*)d_in[0];
    const int*   pos = (const int*)d_in[1];
    const float* q_w = (const float*)d_in[2];
    const float* q_b = (const float*)d_in[3];
    const float* k_w = (const float*)d_in[4];
    const float* k_b = (const float*)d_in[5];
    const float* v_w = (const float*)d_in[6];
    const float* v_b = (const float*)d_in[7];
    const float* o_w = (const float*)d_in[8];
    float* out = (float*)d_out;

    char* ws = (char*)d_ws;
    u16* hsb = (u16*)ws;   ws += (size_t)M_ROWS * HDIM * 2;
    u16* wcat = (u16*)ws;  ws += (size_t)NQKV * HDIM * 2;
    u16* owb = (u16*)ws;   ws += (size_t)HDIM * HDIM * 2;
    float* bcat = (float*)ws; ws += (size_t)NQKV * 4;
    float* tc = (float*)ws;   ws += (size_t)S_LEN * 64 * 4;
    float* ts = (float*)ws;   ws += (size_t)S_LEN * 64 * 4;
    u16* qkv = (u16*)ws;   ws += (size_t)M_ROWS * NQKV * 2;
    u16* Kr = (u16*)ws;    ws += (size_t)B_SZ * NKV_ * S_LEN * HD_ * 2;
    u16* Vr = (u16*)ws;    ws += (size_t)B_SZ * NKV_ * S_LEN * HD_ * 2;
    u16* Qr = hsb;   // alias: hsb dead after QKV GEMM
    u16* Ao = qkv;   // alias: qkv dead after rope_apply

    cvt_f32_bf16<<<(M_ROWS * HDIM / 4 + 255) / 256, 256, 0, stream>>>(hs, hsb, M_ROWS * HDIM / 4);
    cvt_f32_bf16<<<(2048 * 2048 / 4 + 255) / 256, 256, 0, stream>>>(q_w, wcat, 2048 * 2048 / 4);
    cvt_f32_bf16<<<(256 * 2048 / 4 + 255) / 256, 256, 0, stream>>>(k_w, wcat + (size_t)2048 * 2048, 256 * 2048 / 4);
    cvt_f32_bf16<<<(256 * 2048 / 4 + 255) / 256, 256, 0, stream>>>(v_w, wcat + (size_t)2304 * 2048, 256 * 2048 / 4);
    cvt_f32_bf16<<<(2048 * 2048 / 4 + 255) / 256, 256, 0, stream>>>(o_w, owb, 2048 * 2048 / 4);
    concat_bias<<<(NQKV + 255) / 256, 256, 0, stream>>>(q_b, k_b, v_b, bcat);
    rope_table<<<S_LEN, 64, 0, stream>>>(tc, ts);

    gemm256<u16, true><<<dim3(NQKV / 256, M_ROWS / 256), 512, 0, stream>>>(
        hsb, wcat, bcat, qkv, M_ROWS, NQKV, HDIM);

    rope_apply<<<(M_ROWS * 20 * 64 + 255) / 256, 256, 0, stream>>>(qkv, pos, tc, ts, Qr, Kr, Vr);

    attn_kernel<<<dim3(8, B_SZ * NH_), 512, 0, stream>>>(Qr, Kr, Vr, Ao);

    gemm256<float, false><<<dim3(HDIM / 256, M_ROWS / 256), 512, 0, stream>>>(
        Ao, owb, nullptr, out, M_ROWS, HDIM, HDIM);
}